// Round 8
// baseline (838.045 us; speedup 1.0000x reference)
//
#include <hip/hip_runtime.h>
#include <hip/hip_bf16.h>

// GGNN encoder: N=10000, H=512, T=4, E=40000, L=2 x 2 timesteps.
// fp32 inputs, fp32 output, bf16 MFMA internally.
//
// Per step:
//   Msg  = h @ Wmsg_cat^T                (N x 2048, K=512)  [MODE 0, GX=16]
//   inc  = gather-sum(Msg) + cnt*b       (N x 512)          [gather_msum]
//   RZN  = [sig|sig|id]([inc|h] @ Wrzn^T + b) (N x 1536, K=1024) [MODE 1, GX=12]
//   h'   = GRU combine fused into h @ Wnh^T epilogue        [MODE 2, GX=4]
// Final: FC + column-max fused [MODE 3] -> writeout.
//
// GEMM: A staged in LDS (dbuf, global_load_lds w=16); B register-dbuf from a
// pre-packed fragment-order weight image (flatmm-style), vmcnt(6) pipeline.
// EPILOGUE (round 8): LDS-transpose store -- acc frags -> LDS -> contiguous
// int4 stores. Kills the 2x write amplification + 15M scalar-store issue tax
// rocprof exposed (WRITE_SIZE 62MB vs 31MB logical on RZN).

#define NN 10000
#define HD 512
#define NT 4
#define NE 40000
#define CAP 32
#define GYROWS 79          // ceil(10000/128)

typedef __bf16 bf16x8 __attribute__((ext_vector_type(8)));
typedef float f32x4 __attribute__((ext_vector_type(4)));
union V16 { int4 i; bf16x8 b; };
union B4 { double d; __bf16 b[4]; };

typedef __attribute__((address_space(1))) const unsigned int gu32;
typedef __attribute__((address_space(3))) unsigned int lu32;
__device__ __forceinline__ void gll16(const void* g, void* l) {
    __builtin_amdgcn_global_load_lds((gu32*)g, (lu32*)l, 16, 0, 0);
}

__device__ __forceinline__ float bf2f(__hip_bfloat16 v) { return __bfloat162float(v); }
__device__ __forceinline__ float bfl(__bf16 v) { return (float)v; }

// pack 8 fp32 -> int4 of 8 bf16
__device__ __forceinline__ int4 cvt8(const float* __restrict__ s) {
    float4 v0 = *(const float4*)s, v1 = *(const float4*)(s + 4);
    V16 o;
    o.b[0] = (__bf16)v0.x; o.b[1] = (__bf16)v0.y; o.b[2] = (__bf16)v0.z; o.b[3] = (__bf16)v0.w;
    o.b[4] = (__bf16)v1.x; o.b[5] = (__bf16)v1.y; o.b[6] = (__bf16)v1.z; o.b[7] = (__bf16)v1.w;
    return o.i;
}

// Packed-W layout: [ct][kt][s], s=0..511: wc=s>>8, j=(s>>6)&3, lane=s&63.
// Entry = int4 of W[col][kt*32+quad*8 .. +8], col = ct*128+wc*64+j*16+(lane&15),
// quad = (lane>>4)&3.  (Exact B-fragment each lane feeds to mfma_16x16x32.)
__device__ __forceinline__ void pk_decode(int rem, int KTbits, int& col, int& kk) {
    int ct = rem >> (KTbits + 9);
    int r2 = rem & ((1 << (KTbits + 9)) - 1);
    int kt = r2 >> 9, s = r2 & 511;
    int lane = s & 63;
    col = ct * 128 + ((s >> 8) << 6) + (((s >> 6) & 3) << 4) + (lane & 15);
    kk = kt * 32 + ((lane >> 4) & 3) * 8;
}

// ---------------- fused prep: pack weights, init, bins ----------------------
__global__ void prep_all(const float* __restrict__ Wmsg, const float* __restrict__ Wih,
                         const float* __restrict__ Whh, const float* __restrict__ fcW,
                         const float* __restrict__ x, const int* __restrict__ edges,
                         int4* __restrict__ WmPK, int4* __restrict__ WrznPK,
                         int4* __restrict__ WnhPK, int4* __restrict__ WfPK,
                         float* __restrict__ h32, __hip_bfloat16* __restrict__ ab,
                         int* __restrict__ bcnt, int* __restrict__ bins) {
    int blk = blockIdx.x, tid = threadIdx.x;
    if (blk < 1024) {            // WmPK: per layer 16ct x 16kt x 512 = 131072
        int g = blk * 256 + tid;
        int l = g >> 17, rem = g & 131071;
        int col, kk; pk_decode(rem, 4, col, kk);
        WmPK[g] = cvt8(Wmsg + (size_t)l * 1048576 + (size_t)col * 512 + kk);
        return;
    }
    blk -= 1024;
    if (blk < 1536) {            // WrznPK: per layer 12ct x 32kt x 512 = 196608
        int g = blk * 256 + tid;
        int l = g >= 196608;
        int rem = g - l * 196608;
        int col, kk; pk_decode(rem, 5, col, kk);
        int4 v;
        if (kk < 512) {
            v = cvt8(Wih + (size_t)l * 786432 + (size_t)col * 512 + kk);
        } else if (col < 1024) {
            v = cvt8(Whh + (size_t)l * 786432 + (size_t)col * 512 + (kk - 512));
        } else {
            v = make_int4(0, 0, 0, 0);   // n-gate rows, h-half: zero
        }
        WrznPK[g] = v;
        return;
    }
    blk -= 1536;
    if (blk < 256) {             // WnhPK: per layer 4ct x 16kt x 512 = 32768
        int g = blk * 256 + tid;
        int l = g >> 15, rem = g & 32767;
        int col, kk; pk_decode(rem, 4, col, kk);
        WnhPK[g] = cvt8(Whh + (size_t)l * 786432 + 524288 + (size_t)col * 512 + kk);
        return;
    }
    blk -= 256;
    if (blk < 128) {             // WfPK: 4ct x 16kt x 512 = 32768
        int g = blk * 256 + tid;
        int col, kk; pk_decode(g, 4, col, kk);
        WfPK[g] = cvt8(fcW + (size_t)col * 512 + kk);
        return;
    }
    blk -= 128;
    if (blk < 5000) {            // init: h32 <- x, abA h-slot <- bf16(x)
        int i = blk * 1024 + tid * 4;
        float4 v = *(const float4*)(x + i);
        *(float4*)(h32 + i) = v;
        int m = i >> 9, c = i & 511;
        __hip_bfloat16 o[4] = {__float2bfloat16(v.x), __float2bfloat16(v.y),
                               __float2bfloat16(v.z), __float2bfloat16(v.w)};
        *(ulong1*)(ab + (size_t)m * 1024 + 512 + c) = *(ulong1*)o;
        return;
    }
    blk -= 5000;
    {                            // build_bins
        int i = blk * 256 + tid;
        if (i >= NT * NE) return;
        int src = edges[2 * i], tgt = edges[2 * i + 1];
        int t = i / NE;
        int b = tgt * NT + t;
        int pos = atomicAdd(&bcnt[b], 1);
        if (pos < CAP) bins[(size_t)b * CAP + pos] = src;
    }
}

// ---------------- gather: inc[n][c] = sum_t sum_src Msg[src][t*512+c] + cnt*bm
__global__ __launch_bounds__(256) void gather_msum(
    const int* __restrict__ bins, const int* __restrict__ bcnt,
    const float* __restrict__ bm, const __hip_bfloat16* __restrict__ Msg,
    __hip_bfloat16* __restrict__ inc) {
    int wave = threadIdx.x >> 6, lane = threadIdx.x & 63;
    int n = blockIdx.x * 4 + wave;
    int co = lane * 8;
    float acc[8] = {0, 0, 0, 0, 0, 0, 0, 0};
#pragma unroll
    for (int t = 0; t < NT; ++t) {
        int bi = n * NT + t;
        int cnt = bcnt[bi]; if (cnt > CAP) cnt = CAP;
        const int* bl = bins + (size_t)bi * CAP;
        for (int e = 0; e < cnt; ++e) {
            int src = bl[e];
            V16 v; v.i = *(const int4*)(Msg + (size_t)src * 2048 + t * 512 + co);
#pragma unroll
            for (int k = 0; k < 8; ++k) acc[k] += (float)v.b[k];
        }
        float4 b0 = *(const float4*)(bm + t * 512 + co);
        float4 b1 = *(const float4*)(bm + t * 512 + co + 4);
        float fc = (float)cnt;
        acc[0] += fc * b0.x; acc[1] += fc * b0.y; acc[2] += fc * b0.z; acc[3] += fc * b0.w;
        acc[4] += fc * b1.x; acc[5] += fc * b1.y; acc[6] += fc * b1.z; acc[7] += fc * b1.w;
    }
    V16 o;
#pragma unroll
    for (int k = 0; k < 8; ++k) o.b[k] = (__bf16)acc[k];
    *(int4*)(inc + (size_t)n * 1024 + co) = o.i;
}

// ---------------- monotone-uint float max encoding ----------------
__device__ __forceinline__ unsigned fenc(float f) {
    unsigned b = __float_as_uint(f);
    return b ^ (((int)b >> 31) | 0x80000000u);
}
__device__ __forceinline__ float fdec(unsigned u) {
    unsigned b = (u & 0x80000000u) ? (u ^ 0x80000000u) : ~u;
    return __uint_as_float(b);
}

// ---------------- GEMM: out = A(NNxK,lda) @ W^T, 128x128 tile, XCD swizzle ---
template<int MODE, int GX>
__global__ __launch_bounds__(256) void gemm(
    const __hip_bfloat16* __restrict__ A, int lda, int K,
    const int4* __restrict__ Wpk,
    const float* __restrict__ b0, const float* __restrict__ b1,
    const __hip_bfloat16* __restrict__ RZN,
    float* __restrict__ h32, __hip_bfloat16* __restrict__ obf, int ldo,
    unsigned* __restrict__ om) {
    __shared__ int4 sA4[2][512];              // K-loop A staging; epilogue scratch
    __shared__ unsigned sm[128];
    __hip_bfloat16* lds = (__hip_bfloat16*)sA4;   // 8192 bf16 = 64 x 128
    float* ldsF = (float*)sA4;                    // 4096 f32  = 64 x 64
    int bid = blockIdx.x;
    int xcd = bid & 7, slot = bid >> 3;
    int brow = (slot / GX) * 8 + xcd;
    if (brow >= GYROWS) return;
    int bcol = slot % GX;
    int m0 = brow * 128, n0 = bcol * 128;

    int tid = threadIdx.x;
    int lane = tid & 63, wave = tid >> 6;
    int wr = wave >> 1, wc = wave & 1;
    int lm = lane & 15, quad = lane >> 4;

    const int KT = K >> 5;
    const int4* Wp = Wpk + ((size_t)bcol * KT << 9) + wc * 256 + lane;

    auto issueA = [&](int kt, int p) {
        int k0 = kt << 5;
#pragma unroll
        for (int it = 0; it < 2; ++it) {
            int idx = it * 256 + tid;
            int row = idx >> 2, kc = idx & 3;
            int gm = m0 + row; gm = gm < NN ? gm : NN - 1;
            gll16(A + (size_t)gm * lda + k0 + kc * 8, (__hip_bfloat16*)(sA4[p]) + idx * 8);
        }
    };

    f32x4 acc[4][4] = {};
    int4 bbA[4], bbB[4];
    issueA(0, 0);
#pragma unroll
    for (int j = 0; j < 4; ++j) bbA[j] = Wp[j * 64];
    for (int kt = 0; kt < KT; ++kt) {
        int p = kt & 1;
        if (kt + 1 < KT) {
            issueA(kt + 1, 1 - p);
            const int4* wn = Wp + ((kt + 1) << 9);
#pragma unroll
            for (int j = 0; j < 4; ++j) bbB[j] = wn[j * 64];
            __builtin_amdgcn_sched_barrier(0);
            __builtin_amdgcn_s_waitcnt(0xF76);     // vmcnt(6): iter-k A+B done
        } else {
            __builtin_amdgcn_s_waitcnt(0xF70);     // vmcnt(0)
        }
        __builtin_amdgcn_s_barrier();              // tile k staged for all waves
        __builtin_amdgcn_sched_barrier(0);
        V16 a[4];
#pragma unroll
        for (int i = 0; i < 4; ++i)
            a[i].i = sA4[p][(wr * 64 + i * 16 + lm) * 4 + quad];
#pragma unroll
        for (int i = 0; i < 4; ++i) {
#pragma unroll
            for (int j = 0; j < 4; ++j) {
                V16 b; b.i = bbA[j];
                acc[i][j] = __builtin_amdgcn_mfma_f32_16x16x32_bf16(a[i].b, b.b, acc[i][j], 0, 0, 0);
            }
        }
        __builtin_amdgcn_sched_barrier(0);
        __builtin_amdgcn_s_barrier();              // buf p free for iter k+2 DMA
#pragma unroll
        for (int j = 0; j < 4; ++j) bbA[j] = bbB[j];
    }
    // K-loop done (final barrier passed; all waves' LDS reads complete).

    if (MODE == 0 || MODE == 1) {
        // LDS-transpose epilogue, 2 row-phases of 64x128 bf16 (16 KB).
#pragma unroll
        for (int ph = 0; ph < 2; ++ph) {
            if (wr == ph) {
#pragma unroll
                for (int j = 0; j < 4; ++j) {
                    int c = wc * 64 + j * 16 + lm;
                    int col = n0 + c;
                    float bias = (MODE == 1) ? b0[col] + (col < 1024 ? b1[col] : 0.f) : 0.f;
#pragma unroll
                    for (int i = 0; i < 4; ++i)
#pragma unroll
                        for (int r = 0; r < 4; ++r) {
                            float v = acc[i][j][r] + bias;
                            if (MODE == 1 && col < 1024) v = 1.f / (1.f + __expf(-v));
                            lds[(i * 16 + quad * 4 + r) * 128 + c] = __float2bfloat16(v);
                        }
                }
            }
            __syncthreads();
#pragma unroll
            for (int q = 0; q < 4; ++q) {
                int idx = q * 256 + tid;
                int rl = idx >> 4, c16 = idx & 15;
                int m = m0 + ph * 64 + rl;
                if (m < NN)
                    *(int4*)(obf + (size_t)m * ldo + n0 + c16 * 8) =
                        *(const int4*)(lds + rl * 128 + c16 * 8);
            }
            __syncthreads();
        }
    } else if (MODE == 2) {
        // fp32 transpose in 4 quadrant-phases (64x64 f32 = 16 KB), then GRU
        // combine on contiguous 4-wide chunks (vectorized RZN/h32/out access).
#pragma unroll
        for (int ph = 0; ph < 4; ++ph) {
            int pr = ph >> 1, pc = ph & 1;
            if (wr == pr && wc == pc) {
#pragma unroll
                for (int j = 0; j < 4; ++j) {
                    int cc = j * 16 + lm;
                    float bias = b0[n0 + pc * 64 + cc];
#pragma unroll
                    for (int i = 0; i < 4; ++i)
#pragma unroll
                        for (int r = 0; r < 4; ++r)
                            ldsF[(i * 16 + quad * 4 + r) * 64 + cc] = acc[i][j][r] + bias;
                }
            }
            __syncthreads();
#pragma unroll
            for (int q = 0; q < 4; ++q) {
                int idx = q * 256 + tid;
                int rl = idx >> 4, c4 = idx & 15;
                int m = m0 + pr * 64 + rl;
                if (m < NN) {
                    int col0 = n0 + pc * 64 + c4 * 4;
                    float4 v = *(const float4*)(ldsF + rl * 64 + c4 * 4);
                    size_t rzb = (size_t)m * 1536 + col0;
                    B4 rr, zz, nn;
                    rr.d = *(const double*)(RZN + rzb);
                    zz.d = *(const double*)(RZN + rzb + 512);
                    nn.d = *(const double*)(RZN + rzb + 1024);
                    float4 h = *(const float4*)(h32 + (size_t)m * 512 + col0);
                    float vv[4] = {v.x, v.y, v.z, v.w};
                    float hv[4] = {h.x, h.y, h.z, h.w};
                    float ov[4]; B4 ob;
#pragma unroll
                    for (int e = 0; e < 4; ++e) {
                        float nx = bfl(nn.b[e]) + bfl(rr.b[e]) * vv[e];
                        float n = 1.f - 2.f / (__expf(2.f * nx) + 1.f);
                        float z = bfl(zz.b[e]);
                        ov[e] = (1.f - z) * n + z * hv[e];
                        ob.b[e] = (__bf16)ov[e];
                    }
                    *(float4*)(h32 + (size_t)m * 512 + col0) =
                        make_float4(ov[0], ov[1], ov[2], ov[3]);
                    *(double*)(obf + (size_t)m * ldo + col0) = ob.d;
                }
            }
            __syncthreads();
        }
    } else {   // MODE 3: FC + column max (no bulk stores)
        if (tid < 128) sm[tid] = 0;
        __syncthreads();
#pragma unroll
        for (int j = 0; j < 4; ++j) {
            int c = wc * 64 + j * 16 + lm;
            float bias = b0[n0 + c];
            float mx = -INFINITY;
#pragma unroll
            for (int i = 0; i < 4; ++i) {
                int r0 = m0 + wr * 64 + i * 16 + quad * 4;
#pragma unroll
                for (int r = 0; r < 4; ++r) {
                    int m = r0 + r;
                    if (m < NN) mx = fmaxf(mx, acc[i][j][r] + bias);
                }
            }
            atomicMax(&sm[c], fenc(mx));
        }
        __syncthreads();
        if (tid < 128) atomicMax(&om[n0 + tid], sm[tid]);
    }
}

__global__ void writeout(const unsigned* __restrict__ om, float* __restrict__ o) {
    int c = threadIdx.x;
    o[c] = fdec(om[c]);
}

// ---------------- launch ----------------
extern "C" void kernel_launch(void* const* d_in, const int* in_sizes, int n_in,
                              void* d_out, int out_size, void* d_ws, size_t ws_size,
                              hipStream_t stream) {
    (void)in_sizes; (void)n_in; (void)out_size; (void)ws_size;
    const float* x    = (const float*)d_in[0];
    const int*   edges= (const int*)d_in[1];
    const float* Wmsg = (const float*)d_in[2];
    const float* bmsg = (const float*)d_in[3];
    const float* Wih  = (const float*)d_in[4];
    const float* Whh  = (const float*)d_in[5];
    const float* bih  = (const float*)d_in[6];
    const float* bhh  = (const float*)d_in[7];
    const float* fcW  = (const float*)d_in[8];
    const float* fcb  = (const float*)d_in[9];
    float* out = (float*)d_out;

    char* ws = (char*)d_ws;
    size_t off = 0;
    auto alloc = [&](size_t bytes) -> void* {
        void* p = ws + off; off += (bytes + 255) & ~(size_t)255; return p;
    };
    float*          h32  = (float*)alloc((size_t)NN * HD * 4);              // 20.5 MB
    __hip_bfloat16* abA  = (__hip_bfloat16*)alloc((size_t)NN * 1024 * 2);   // 20.5 MB
    __hip_bfloat16* abB  = (__hip_bfloat16*)alloc((size_t)NN * 1024 * 2);   // 20.5 MB
    int*            bcnt = (int*)alloc((size_t)NN * NT * 4);                // 160 KB
    int*            bins = (int*)alloc((size_t)NN * NT * CAP * 4);          // 5.1 MB
    unsigned*       om   = (unsigned*)alloc(HD * 4);
    int4*           WmPK  = (int4*)alloc((size_t)2 * 131072 * 16);          // 4.2 MB
    int4*           WrznPK= (int4*)alloc((size_t)2 * 196608 * 16);          // 6.3 MB
    int4*           WnhPK = (int4*)alloc((size_t)2 * 32768 * 16);           // 1.05 MB
    int4*           WfPK  = (int4*)alloc((size_t)32768 * 16);               // 0.5 MB
    // union: Msg (41 MB) xor RZN (30.7 MB)
    char* uni = (char*)alloc((size_t)NN * 2048 * 2);                        // 41 MB
    __hip_bfloat16* Msg = (__hip_bfloat16*)uni;
    __hip_bfloat16* RZN = (__hip_bfloat16*)uni;
    // total ~120 MB

    hipMemsetAsync(bcnt, 0, (size_t)NN * NT * 4, stream);
    hipMemsetAsync(om, 0, HD * 4, stream);
    prep_all<<<1024 + 1536 + 256 + 128 + 5000 + 625, 256, 0, stream>>>(
        Wmsg, Wih, Whh, fcW, x, edges, WmPK, WrznPK, WnhPK, WfPK, h32, abA, bcnt, bins);

    for (int s = 0; s < 4; ++s) {
        int layer = s >> 1;
        __hip_bfloat16* cur = (s & 1) ? abB : abA;
        __hip_bfloat16* nxt = (s & 1) ? abA : abB;
        const int4* Wm = WmPK + (size_t)layer * 131072;
        const int4* Wz = WrznPK + (size_t)layer * 196608;
        const int4* Wn_h = WnhPK + (size_t)layer * 32768;
        const float* bm = bmsg + (size_t)layer * 2048;
        const float* bi = bih + (size_t)layer * 1536;
        const float* bh = bhh + (size_t)layer * 1536;

        // Msg = h @ Wm^T  (out 2048, K=512)
        gemm<0, 16><<<16 * 80, 256, 0, stream>>>(cur + 512, 1024, 512, Wm,
            nullptr, nullptr, nullptr, nullptr, Msg, 2048, nullptr);
        // inc = gather(Msg) + cnt*bm -> cur[0:512]
        gather_msum<<<NN / 4, 256, 0, stream>>>(bins, bcnt, bm, Msg, cur);
        // RZN = [sig r | sig z | i_n] = [inc|h] @ Wrzn^T + bi + bh(r,z)
        gemm<1, 12><<<12 * 80, 256, 0, stream>>>(cur, 1024, 1024, Wz,
            bi, bh, nullptr, nullptr, RZN, 1536, nullptr);
        // GRU combine fused into h @ Wnh^T epilogue -> h32, nxt h-slot
        gemm<2, 4><<<4 * 80, 256, 0, stream>>>(cur + 512, 1024, 512, Wn_h,
            bh + 1024, nullptr, RZN, h32, nxt + 512, 1024, nullptr);
    }
    // FC + column max (final h in abA h-slot after 4 steps)
    gemm<3, 4><<<4 * 80, 256, 0, stream>>>(abA + 512, 1024, 512, WfPK,
        fcb, nullptr, nullptr, nullptr, nullptr, 0, om);
    writeout<<<1, 512, 0, stream>>>(om, out);
}

// Round 9
// 771.139 us; speedup vs baseline: 1.0868x; 1.0868x over previous
//
#include <hip/hip_runtime.h>
#include <hip/hip_bf16.h>

// GGNN encoder: N=10000, H=512, T=4, E=40000, L=2 x 2 timesteps.
// fp32 inputs, fp32 output, bf16 MFMA internally.
//
// Per step (2 GEMM dispatches -- algebraic minimum FLOPs 52.5 GF):
//   Msg  = h @ Wmsg_cat^T              (N x 2048, K=512)   [MODE 0]
//   inc  = gather-sum(Msg) + cnt*b     (N x 512)           [gather_msum]
//   RZNH = [sig r|sig z|i_n|hn] = [inc|h] @ Wrznh^T + b  (N x 2048, K=1024,
//          per-bcol K-range skips the structurally-zero halves) [MODE 1]
//   h'   = elementwise GRU combine (tanh/blend)            [gru_ew]
// Final: FC + column-max fused [MODE 3] -> writeout.
//
// GEMM: plain 2D grid (r5-r8 XCD swizzle REVERTED: it cost 15-25us/dispatch
// while saving HBM fetch we didn't need -- r4 measured 53us vs r5+ 68-78us).
// A staged in LDS (dbuf global_load_lds w=16); B register-dbuf from packed
// fragment-order weights; vmcnt(6) pipeline; LDS-transpose coalesced epilogue.

#define NN 10000
#define HD 512
#define NT 4
#define NE 40000
#define CAP 24          // max edges per (target,type); P(Poisson(4)>24)~1e-14/bin
#define GYROWS 79       // ceil(10000/128)

typedef __bf16 bf16x8 __attribute__((ext_vector_type(8)));
typedef float f32x4 __attribute__((ext_vector_type(4)));
union V16 { int4 i; bf16x8 b; };

typedef __attribute__((address_space(1))) const unsigned int gu32;
typedef __attribute__((address_space(3))) unsigned int lu32;
__device__ __forceinline__ void gll16(const void* g, void* l) {
    __builtin_amdgcn_global_load_lds((gu32*)g, (lu32*)l, 16, 0, 0);
}

__device__ __forceinline__ float bfl(__bf16 v) { return (float)v; }

// pack 8 fp32 -> int4 of 8 bf16
__device__ __forceinline__ int4 cvt8(const float* __restrict__ s) {
    float4 v0 = *(const float4*)s, v1 = *(const float4*)(s + 4);
    V16 o;
    o.b[0] = (__bf16)v0.x; o.b[1] = (__bf16)v0.y; o.b[2] = (__bf16)v0.z; o.b[3] = (__bf16)v0.w;
    o.b[4] = (__bf16)v1.x; o.b[5] = (__bf16)v1.y; o.b[6] = (__bf16)v1.z; o.b[7] = (__bf16)v1.w;
    return o.i;
}

// Packed-W layout: [ct][kt][s], s=0..511: wc=s>>8, j=(s>>6)&3, lane=s&63.
// Entry = int4 of W[col][kt*32+quad*8 .. +8], col = ct*128+wc*64+j*16+(lane&15).
__device__ __forceinline__ void pk_decode(int rem, int KTbits, int& col, int& kk) {
    int ct = rem >> (KTbits + 9);
    int r2 = rem & ((1 << (KTbits + 9)) - 1);
    int kt = r2 >> 9, s = r2 & 511;
    int lane = s & 63;
    col = ct * 128 + ((s >> 8) << 6) + (((s >> 6) & 3) << 4) + (lane & 15);
    kk = kt * 32 + ((lane >> 4) & 3) * 8;
}

// ---------------- fused prep: pack weights, init, bins ----------------------
// SEG0 WmPK 1024 blk | SEG1 WrznhPK 2048 | SEG2 WfPK 128 | SEG3 init 5000 |
// SEG4 bins 625.
__global__ void prep_all(const float* __restrict__ Wmsg, const float* __restrict__ Wih,
                         const float* __restrict__ Whh, const float* __restrict__ fcW,
                         const float* __restrict__ x, const int* __restrict__ edges,
                         int4* __restrict__ WmPK, int4* __restrict__ WrznhPK,
                         int4* __restrict__ WfPK,
                         float* __restrict__ h32, __hip_bfloat16* __restrict__ ab,
                         int* __restrict__ bcnt, int* __restrict__ bins) {
    int blk = blockIdx.x, tid = threadIdx.x;
    if (blk < 1024) {            // WmPK: per layer 16ct x 16kt x 512 = 131072
        int g = blk * 256 + tid;
        int l = g >> 17, rem = g & 131071;
        int col, kk; pk_decode(rem, 4, col, kk);
        WmPK[g] = cvt8(Wmsg + (size_t)l * 1048576 + (size_t)col * 512 + kk);
        return;
    }
    blk -= 1024;
    if (blk < 2048) {            // WrznhPK: per layer 16ct x 32kt x 512 = 262144
        int g = blk * 256 + tid;
        int l = g >> 18, rem = g & 262143;
        int col, kk; pk_decode(rem, 5, col, kk);
        int gate = col >> 9, cc = col & 511;   // 0:r 1:z 2:i_n 3:hn
        int4 v = make_int4(0, 0, 0, 0);
        if (kk < 512) {
            if (gate <= 2) v = cvt8(Wih + (size_t)l * 786432 + (size_t)(gate * 512 + cc) * 512 + kk);
        } else {
            if (gate <= 1) v = cvt8(Whh + (size_t)l * 786432 + (size_t)(gate * 512 + cc) * 512 + (kk - 512));
            else if (gate == 3) v = cvt8(Whh + (size_t)l * 786432 + (size_t)(1024 + cc) * 512 + (kk - 512));
        }
        WrznhPK[g] = v;
        return;
    }
    blk -= 2048;
    if (blk < 128) {             // WfPK: 4ct x 16kt x 512 = 32768
        int g = blk * 256 + tid;
        int col, kk; pk_decode(g, 4, col, kk);
        WfPK[g] = cvt8(fcW + (size_t)col * 512 + kk);
        return;
    }
    blk -= 128;
    if (blk < 5000) {            // init: h32 <- x, abA h-slot <- bf16(x)
        int i = blk * 1024 + tid * 4;
        float4 v = *(const float4*)(x + i);
        *(float4*)(h32 + i) = v;
        int m = i >> 9, c = i & 511;
        __hip_bfloat16 o[4] = {__float2bfloat16(v.x), __float2bfloat16(v.y),
                               __float2bfloat16(v.z), __float2bfloat16(v.w)};
        *(ulong1*)(ab + (size_t)m * 1024 + 512 + c) = *(ulong1*)o;
        return;
    }
    blk -= 5000;
    {                            // build_bins
        int i = blk * 256 + tid;
        if (i >= NT * NE) return;
        int src = edges[2 * i], tgt = edges[2 * i + 1];
        int t = i / NE;
        int b = tgt * NT + t;
        int pos = atomicAdd(&bcnt[b], 1);
        if (pos < CAP) bins[(size_t)b * CAP + pos] = src;
    }
}

// ---------------- gather: inc[n][c] = sum_t sum_src Msg[src][t*512+c] + cnt*bm
__global__ __launch_bounds__(256) void gather_msum(
    const int* __restrict__ bins, const int* __restrict__ bcnt,
    const float* __restrict__ bm, const __hip_bfloat16* __restrict__ Msg,
    __hip_bfloat16* __restrict__ inc) {
    int wave = threadIdx.x >> 6, lane = threadIdx.x & 63;
    int n = blockIdx.x * 4 + wave;
    int co = lane * 8;
    float acc[8] = {0, 0, 0, 0, 0, 0, 0, 0};
#pragma unroll
    for (int t = 0; t < NT; ++t) {
        int bi = n * NT + t;
        int cnt = bcnt[bi]; if (cnt > CAP) cnt = CAP;
        const int* bl = bins + (size_t)bi * CAP;
        for (int e = 0; e < cnt; ++e) {
            int src = bl[e];
            V16 v; v.i = *(const int4*)(Msg + (size_t)src * 2048 + t * 512 + co);
#pragma unroll
            for (int k = 0; k < 8; ++k) acc[k] += (float)v.b[k];
        }
        float4 b0 = *(const float4*)(bm + t * 512 + co);
        float4 b1 = *(const float4*)(bm + t * 512 + co + 4);
        float fc = (float)cnt;
        acc[0] += fc * b0.x; acc[1] += fc * b0.y; acc[2] += fc * b0.z; acc[3] += fc * b0.w;
        acc[4] += fc * b1.x; acc[5] += fc * b1.y; acc[6] += fc * b1.z; acc[7] += fc * b1.w;
    }
    V16 o;
#pragma unroll
    for (int k = 0; k < 8; ++k) o.b[k] = (__bf16)acc[k];
    *(int4*)(inc + (size_t)n * 1024 + co) = o.i;
}

// ---------------- elementwise GRU combine ----------------
// G = RZNH (N x 2048 bf16). h' = (1-z)*tanh(i_n + r*hn) + z*h32.
__global__ __launch_bounds__(256) void gru_ew(
    const __hip_bfloat16* __restrict__ G, float* __restrict__ h32,
    __hip_bfloat16* __restrict__ hbO) {
    int i = (blockIdx.x * 256 + threadIdx.x) * 8;   // over N*512, grid 2500
    int m = i >> 9, c = i & 511;
    const __hip_bfloat16* g = G + (size_t)m * 2048 + c;
    V16 r, z, nb, hn;
    r.i  = *(const int4*)g;
    z.i  = *(const int4*)(g + 512);
    nb.i = *(const int4*)(g + 1024);
    hn.i = *(const int4*)(g + 1536);
    float4 h0 = *(const float4*)(h32 + i), h1 = *(const float4*)(h32 + i + 4);
    float hv[8] = {h0.x, h0.y, h0.z, h0.w, h1.x, h1.y, h1.z, h1.w};
    float ov[8]; V16 ob;
#pragma unroll
    for (int e = 0; e < 8; ++e) {
        float nx = bfl(nb.b[e]) + bfl(r.b[e]) * bfl(hn.b[e]);
        float n = 1.f - 2.f / (__expf(2.f * nx) + 1.f);
        float zv = bfl(z.b[e]);
        ov[e] = (1.f - zv) * n + zv * hv[e];
        ob.b[e] = (__bf16)ov[e];
    }
    *(float4*)(h32 + i)     = make_float4(ov[0], ov[1], ov[2], ov[3]);
    *(float4*)(h32 + i + 4) = make_float4(ov[4], ov[5], ov[6], ov[7]);
    *(int4*)(hbO + (size_t)m * 1024 + c) = ob.i;
}

// ---------------- monotone-uint float max encoding ----------------
__device__ __forceinline__ unsigned fenc(float f) {
    unsigned b = __float_as_uint(f);
    return b ^ (((int)b >> 31) | 0x80000000u);
}
__device__ __forceinline__ float fdec(unsigned u) {
    unsigned b = (u & 0x80000000u) ? (u ^ 0x80000000u) : ~u;
    return __uint_as_float(b);
}

// ---------------- GEMM: out = A(NNxK,lda) @ W^T, 128x128 tile, 2D grid -------
// MODE 0: obf = bf16(acc)                      (Msg)
// MODE 1: gates: col<1024 sigmoid(acc+b0+b1); col<1536 acc+b0; else acc+b1[col-512]
//         (per-bcol K-range: i_n cols use kt<16, hn cols use kt>=16)
// MODE 3: column max of acc+b0 -> om           (FC)
template<int MODE>
__global__ __launch_bounds__(256) void gemm(
    const __hip_bfloat16* __restrict__ A, int lda, int K,
    const int4* __restrict__ Wpk,
    const float* __restrict__ b0, const float* __restrict__ b1,
    __hip_bfloat16* __restrict__ obf, int ldo,
    unsigned* __restrict__ om) {
    __shared__ int4 sA4[2][512];              // K-loop A staging; epilogue scratch
    __shared__ unsigned sm[128];
    __hip_bfloat16* lds = (__hip_bfloat16*)sA4;   // 8192 bf16 = 64 x 128
    int bcol = blockIdx.x, brow = blockIdx.y;
    int m0 = brow * 128, n0 = bcol * 128;

    int tid = threadIdx.x;
    int lane = tid & 63, wave = tid >> 6;
    int wr = wave >> 1, wc = wave & 1;
    int lm = lane & 15, quad = lane >> 4;

    const int KT = K >> 5;
    int kbeg = 0, kend = KT;
    if (MODE == 1) {             // skip structurally-zero K halves
        if (bcol >= 12) kbeg = 16;       // hn: inc-half of W is zero
        else if (bcol >= 8) kend = 16;   // i_n: h-half of W is zero
    }
    const int4* Wp = Wpk + ((size_t)bcol * KT << 9) + wc * 256 + lane;

    auto issueA = [&](int kt, int p) {
        int k0 = kt << 5;
#pragma unroll
        for (int it = 0; it < 2; ++it) {
            int idx = it * 256 + tid;
            int row = idx >> 2, kc = idx & 3;
            int gm = m0 + row; gm = gm < NN ? gm : NN - 1;
            gll16(A + (size_t)gm * lda + k0 + kc * 8, (__hip_bfloat16*)(sA4[p]) + idx * 8);
        }
    };

    f32x4 acc[4][4] = {};
    int4 bbA[4], bbB[4];
    issueA(kbeg, 0);
#pragma unroll
    for (int j = 0; j < 4; ++j) bbA[j] = Wp[(kbeg << 9) + j * 64];
    for (int kt = kbeg; kt < kend; ++kt) {
        int p = (kt - kbeg) & 1;
        if (kt + 1 < kend) {
            issueA(kt + 1, 1 - p);
            const int4* wn = Wp + ((size_t)(kt + 1) << 9);
#pragma unroll
            for (int j = 0; j < 4; ++j) bbB[j] = wn[j * 64];
            __builtin_amdgcn_sched_barrier(0);
            __builtin_amdgcn_s_waitcnt(0xF76);     // vmcnt(6): iter-k A+B done
        } else {
            __builtin_amdgcn_s_waitcnt(0xF70);     // vmcnt(0)
        }
        __builtin_amdgcn_s_barrier();              // tile k staged for all waves
        __builtin_amdgcn_sched_barrier(0);
        V16 a[4];
#pragma unroll
        for (int i = 0; i < 4; ++i)
            a[i].i = sA4[p][(wr * 64 + i * 16 + lm) * 4 + quad];
#pragma unroll
        for (int i = 0; i < 4; ++i) {
#pragma unroll
            for (int j = 0; j < 4; ++j) {
                V16 b; b.i = bbA[j];
                acc[i][j] = __builtin_amdgcn_mfma_f32_16x16x32_bf16(a[i].b, b.b, acc[i][j], 0, 0, 0);
            }
        }
        __builtin_amdgcn_sched_barrier(0);
        __builtin_amdgcn_s_barrier();              // buf p free for iter k+2 DMA
#pragma unroll
        for (int j = 0; j < 4; ++j) bbA[j] = bbB[j];
    }

    if (MODE == 0 || MODE == 1) {
        // LDS-transpose epilogue, 2 row-phases of 64x128 bf16 (coalesced stores)
#pragma unroll
        for (int ph = 0; ph < 2; ++ph) {
            if (wr == ph) {
#pragma unroll
                for (int j = 0; j < 4; ++j) {
                    int c = wc * 64 + j * 16 + lm;
                    int col = n0 + c;
                    float bias = 0.f;
                    if (MODE == 1) {
                        if (col < 1024) bias = b0[col] + b1[col];
                        else if (col < 1536) bias = b0[col];
                        else bias = b1[col - 512];
                    }
#pragma unroll
                    for (int i = 0; i < 4; ++i)
#pragma unroll
                        for (int r = 0; r < 4; ++r) {
                            float v = acc[i][j][r] + bias;
                            if (MODE == 1 && col < 1024) v = 1.f / (1.f + __expf(-v));
                            lds[(i * 16 + quad * 4 + r) * 128 + c] = __float2bfloat16(v);
                        }
                }
            }
            __syncthreads();
#pragma unroll
            for (int q = 0; q < 4; ++q) {
                int idx = q * 256 + tid;
                int rl = idx >> 4, c16 = idx & 15;
                int m = m0 + ph * 64 + rl;
                if (m < NN)
                    *(int4*)(obf + (size_t)m * ldo + n0 + c16 * 8) =
                        *(const int4*)(lds + rl * 128 + c16 * 8);
            }
            __syncthreads();
        }
    } else {   // MODE 3: FC + column max
        if (tid < 128) sm[tid] = 0;
        __syncthreads();
#pragma unroll
        for (int j = 0; j < 4; ++j) {
            int c = wc * 64 + j * 16 + lm;
            float bias = b0[n0 + c];
            float mx = -INFINITY;
#pragma unroll
            for (int i = 0; i < 4; ++i) {
                int r0 = m0 + wr * 64 + i * 16 + quad * 4;
#pragma unroll
                for (int r = 0; r < 4; ++r) {
                    int m = r0 + r;
                    if (m < NN) mx = fmaxf(mx, acc[i][j][r] + bias);
                }
            }
            atomicMax(&sm[c], fenc(mx));
        }
        __syncthreads();
        if (tid < 128) atomicMax(&om[n0 + tid], sm[tid]);
    }
}

__global__ void writeout(const unsigned* __restrict__ om, float* __restrict__ o) {
    int c = threadIdx.x;
    o[c] = fdec(om[c]);
}

// ---------------- launch ----------------
extern "C" void kernel_launch(void* const* d_in, const int* in_sizes, int n_in,
                              void* d_out, int out_size, void* d_ws, size_t ws_size,
                              hipStream_t stream) {
    (void)in_sizes; (void)n_in; (void)out_size; (void)ws_size;
    const float* x    = (const float*)d_in[0];
    const int*   edges= (const int*)d_in[1];
    const float* Wmsg = (const float*)d_in[2];
    const float* bmsg = (const float*)d_in[3];
    const float* Wih  = (const float*)d_in[4];
    const float* Whh  = (const float*)d_in[5];
    const float* bih  = (const float*)d_in[6];
    const float* bhh  = (const float*)d_in[7];
    const float* fcW  = (const float*)d_in[8];
    const float* fcb  = (const float*)d_in[9];
    float* out = (float*)d_out;

    char* ws = (char*)d_ws;
    size_t off = 0;
    auto alloc = [&](size_t bytes) -> void* {
        void* p = ws + off; off += (bytes + 255) & ~(size_t)255; return p;
    };
    float*          h32  = (float*)alloc((size_t)NN * HD * 4);              // 20.5 MB
    __hip_bfloat16* abA  = (__hip_bfloat16*)alloc((size_t)NN * 1024 * 2);   // 20.5 MB
    __hip_bfloat16* abB  = (__hip_bfloat16*)alloc((size_t)NN * 1024 * 2);   // 20.5 MB
    int*            bcnt = (int*)alloc((size_t)NN * NT * 4);                // 160 KB
    int*            bins = (int*)alloc((size_t)NN * NT * CAP * 4);          // 3.8 MB
    unsigned*       om   = (unsigned*)alloc(HD * 4);
    int4*           WmPK   = (int4*)alloc((size_t)2 * 131072 * 16);         // 4.2 MB
    int4*           WrznhPK= (int4*)alloc((size_t)2 * 262144 * 16);         // 8.4 MB
    int4*           WfPK   = (int4*)alloc((size_t)32768 * 16);              // 0.5 MB
    // union: Msg (41 MB) xor RZNH (41 MB)
    char* uni = (char*)alloc((size_t)NN * 2048 * 2);                        // 41 MB
    __hip_bfloat16* Msg  = (__hip_bfloat16*)uni;
    __hip_bfloat16* RZNH = (__hip_bfloat16*)uni;
    // total ~119.5 MB

    hipMemsetAsync(bcnt, 0, (size_t)NN * NT * 4, stream);
    hipMemsetAsync(om, 0, HD * 4, stream);
    prep_all<<<1024 + 2048 + 128 + 5000 + 625, 256, 0, stream>>>(
        Wmsg, Wih, Whh, fcW, x, edges, WmPK, WrznhPK, WfPK, h32, abA, bcnt, bins);

    for (int s = 0; s < 4; ++s) {
        int layer = s >> 1;
        __hip_bfloat16* cur = (s & 1) ? abB : abA;
        __hip_bfloat16* nxt = (s & 1) ? abA : abB;
        const int4* Wm = WmPK + (size_t)layer * 131072;
        const int4* Wz = WrznhPK + (size_t)layer * 262144;
        const float* bm = bmsg + (size_t)layer * 2048;
        const float* bi = bih + (size_t)layer * 1536;
        const float* bh = bhh + (size_t)layer * 1536;

        // Msg = h @ Wm^T  (out 2048, K=512)
        gemm<0><<<dim3(16, GYROWS), 256, 0, stream>>>(cur + 512, 1024, 512, Wm,
            nullptr, nullptr, Msg, 2048, nullptr);
        // inc = gather(Msg) + cnt*bm -> cur[0:512]
        gather_msum<<<NN / 4, 256, 0, stream>>>(bins, bcnt, bm, Msg, cur);
        // RZNH = [sig r | sig z | i_n | hn]  (out 2048, K=1024)
        gemm<1><<<dim3(16, GYROWS), 256, 0, stream>>>(cur, 1024, 1024, Wz,
            bi, bh, RZNH, 2048, nullptr);
        // elementwise GRU combine -> h32, nxt h-slot
        gru_ew<<<NN / 4, 256, 0, stream>>>(RZNH, h32, nxt + 512);
    }
    // FC + column max (final h in abA h-slot after 4 steps)
    gemm<3><<<dim3(4, GYROWS), 256, 0, stream>>>(abA + 512, 1024, 512, WfPK,
        fcb, nullptr, nullptr, 0, om);
    writeout<<<1, 512, 0, stream>>>(om, out);
}

// Round 10
// 759.283 us; speedup vs baseline: 1.1037x; 1.0156x over previous
//
#include <hip/hip_runtime.h>
#include <hip/hip_bf16.h>

// GGNN encoder: N=10000, H=512, T=4, E=40000, L=2 x 2 timesteps.
// fp32 inputs, fp32 output, bf16 MFMA internally.
//
// Per step (2 GEMM dispatches -- algebraic minimum FLOPs 52.5 GF):
//   Msg  = h @ Wmsg_cat^T              (N x 2048, K=512)   [MODE 0]
//   inc  = gather-sum(Msg) + cnt*b     (N x 512)           [gather_msum]
//   RZNH = [sig r|sig z|i_n|hn] = [inc|h] @ Wrznh^T + b  (N x 2048, K=1024,
//          per-bcol K-range skips the structurally-zero halves) [MODE 1]
//   h'   = elementwise GRU combine (tanh/blend)            [gru_ew]
// Final: FC + column-max fused [MODE 3] -> writeout.
//
// GEMM r10: DEPTH-2 software pipeline. A staged via global_load_lds into 3
// rotating LDS buffers (2 tiles in flight); B register-dbuf from packed
// fragment-order weights (L2-resident, depth-1). Wait ladder vmcnt(8/6/0)
// drains only the tile about to be consumed. Plain 2D grid (XCD swizzle
// measured harmful r5-r8). LDS-transpose coalesced epilogue.

#define NN 10000
#define HD 512
#define NT 4
#define NE 40000
#define CAP 24          // max edges per (target,type); P(Poisson(4)>24)~1e-14/bin
#define GYROWS 79       // ceil(10000/128)

typedef __bf16 bf16x8 __attribute__((ext_vector_type(8)));
typedef float f32x4 __attribute__((ext_vector_type(4)));
union V16 { int4 i; bf16x8 b; };

typedef __attribute__((address_space(1))) const unsigned int gu32;
typedef __attribute__((address_space(3))) unsigned int lu32;
__device__ __forceinline__ void gll16(const void* g, void* l) {
    __builtin_amdgcn_global_load_lds((gu32*)g, (lu32*)l, 16, 0, 0);
}

__device__ __forceinline__ float bfl(__bf16 v) { return (float)v; }

// pack 8 fp32 -> int4 of 8 bf16
__device__ __forceinline__ int4 cvt8(const float* __restrict__ s) {
    float4 v0 = *(const float4*)s, v1 = *(const float4*)(s + 4);
    V16 o;
    o.b[0] = (__bf16)v0.x; o.b[1] = (__bf16)v0.y; o.b[2] = (__bf16)v0.z; o.b[3] = (__bf16)v0.w;
    o.b[4] = (__bf16)v1.x; o.b[5] = (__bf16)v1.y; o.b[6] = (__bf16)v1.z; o.b[7] = (__bf16)v1.w;
    return o.i;
}

// Packed-W layout: [ct][kt][s], s=0..511: wc=s>>8, j=(s>>6)&3, lane=s&63.
// Entry = int4 of W[col][kt*32+quad*8 .. +8], col = ct*128+wc*64+j*16+(lane&15).
__device__ __forceinline__ void pk_decode(int rem, int KTbits, int& col, int& kk) {
    int ct = rem >> (KTbits + 9);
    int r2 = rem & ((1 << (KTbits + 9)) - 1);
    int kt = r2 >> 9, s = r2 & 511;
    int lane = s & 63;
    col = ct * 128 + ((s >> 8) << 6) + (((s >> 6) & 3) << 4) + (lane & 15);
    kk = kt * 32 + ((lane >> 4) & 3) * 8;
}

// ---------------- fused prep: pack weights, init, bins ----------------------
__global__ void prep_all(const float* __restrict__ Wmsg, const float* __restrict__ Wih,
                         const float* __restrict__ Whh, const float* __restrict__ fcW,
                         const float* __restrict__ x, const int* __restrict__ edges,
                         int4* __restrict__ WmPK, int4* __restrict__ WrznhPK,
                         int4* __restrict__ WfPK,
                         float* __restrict__ h32, __hip_bfloat16* __restrict__ ab,
                         int* __restrict__ bcnt, int* __restrict__ bins) {
    int blk = blockIdx.x, tid = threadIdx.x;
    if (blk < 1024) {            // WmPK: per layer 16ct x 16kt x 512 = 131072
        int g = blk * 256 + tid;
        int l = g >> 17, rem = g & 131071;
        int col, kk; pk_decode(rem, 4, col, kk);
        WmPK[g] = cvt8(Wmsg + (size_t)l * 1048576 + (size_t)col * 512 + kk);
        return;
    }
    blk -= 1024;
    if (blk < 2048) {            // WrznhPK: per layer 16ct x 32kt x 512 = 262144
        int g = blk * 256 + tid;
        int l = g >> 18, rem = g & 262143;
        int col, kk; pk_decode(rem, 5, col, kk);
        int gate = col >> 9, cc = col & 511;   // 0:r 1:z 2:i_n 3:hn
        int4 v = make_int4(0, 0, 0, 0);
        if (kk < 512) {
            if (gate <= 2) v = cvt8(Wih + (size_t)l * 786432 + (size_t)(gate * 512 + cc) * 512 + kk);
        } else {
            if (gate <= 1) v = cvt8(Whh + (size_t)l * 786432 + (size_t)(gate * 512 + cc) * 512 + (kk - 512));
            else if (gate == 3) v = cvt8(Whh + (size_t)l * 786432 + (size_t)(1024 + cc) * 512 + (kk - 512));
        }
        WrznhPK[g] = v;
        return;
    }
    blk -= 2048;
    if (blk < 128) {             // WfPK: 4ct x 16kt x 512 = 32768
        int g = blk * 256 + tid;
        int col, kk; pk_decode(g, 4, col, kk);
        WfPK[g] = cvt8(fcW + (size_t)col * 512 + kk);
        return;
    }
    blk -= 128;
    if (blk < 5000) {            // init: h32 <- x, abA h-slot <- bf16(x)
        int i = blk * 1024 + tid * 4;
        float4 v = *(const float4*)(x + i);
        *(float4*)(h32 + i) = v;
        int m = i >> 9, c = i & 511;
        __hip_bfloat16 o[4] = {__float2bfloat16(v.x), __float2bfloat16(v.y),
                               __float2bfloat16(v.z), __float2bfloat16(v.w)};
        *(ulong1*)(ab + (size_t)m * 1024 + 512 + c) = *(ulong1*)o;
        return;
    }
    blk -= 5000;
    {                            // build_bins
        int i = blk * 256 + tid;
        if (i >= NT * NE) return;
        int src = edges[2 * i], tgt = edges[2 * i + 1];
        int t = i / NE;
        int b = tgt * NT + t;
        int pos = atomicAdd(&bcnt[b], 1);
        if (pos < CAP) bins[(size_t)b * CAP + pos] = src;
    }
}

// ---------------- gather: inc[n][c] = sum_t sum_src Msg[src][t*512+c] + cnt*bm
__global__ __launch_bounds__(256) void gather_msum(
    const int* __restrict__ bins, const int* __restrict__ bcnt,
    const float* __restrict__ bm, const __hip_bfloat16* __restrict__ Msg,
    __hip_bfloat16* __restrict__ inc) {
    int wave = threadIdx.x >> 6, lane = threadIdx.x & 63;
    int n = blockIdx.x * 4 + wave;
    int co = lane * 8;
    float acc[8] = {0, 0, 0, 0, 0, 0, 0, 0};
#pragma unroll
    for (int t = 0; t < NT; ++t) {
        int bi = n * NT + t;
        int cnt = bcnt[bi]; if (cnt > CAP) cnt = CAP;
        const int* bl = bins + (size_t)bi * CAP;
        for (int e = 0; e < cnt; ++e) {
            int src = bl[e];
            V16 v; v.i = *(const int4*)(Msg + (size_t)src * 2048 + t * 512 + co);
#pragma unroll
            for (int k = 0; k < 8; ++k) acc[k] += (float)v.b[k];
        }
        float4 b0 = *(const float4*)(bm + t * 512 + co);
        float4 b1 = *(const float4*)(bm + t * 512 + co + 4);
        float fc = (float)cnt;
        acc[0] += fc * b0.x; acc[1] += fc * b0.y; acc[2] += fc * b0.z; acc[3] += fc * b0.w;
        acc[4] += fc * b1.x; acc[5] += fc * b1.y; acc[6] += fc * b1.z; acc[7] += fc * b1.w;
    }
    V16 o;
#pragma unroll
    for (int k = 0; k < 8; ++k) o.b[k] = (__bf16)acc[k];
    *(int4*)(inc + (size_t)n * 1024 + co) = o.i;
}

// ---------------- elementwise GRU combine ----------------
__global__ __launch_bounds__(256) void gru_ew(
    const __hip_bfloat16* __restrict__ G, float* __restrict__ h32,
    __hip_bfloat16* __restrict__ hbO) {
    int i = (blockIdx.x * 256 + threadIdx.x) * 8;   // over N*512, grid 2500
    int m = i >> 9, c = i & 511;
    const __hip_bfloat16* g = G + (size_t)m * 2048 + c;
    V16 r, z, nb, hn;
    r.i  = *(const int4*)g;
    z.i  = *(const int4*)(g + 512);
    nb.i = *(const int4*)(g + 1024);
    hn.i = *(const int4*)(g + 1536);
    float4 h0 = *(const float4*)(h32 + i), h1 = *(const float4*)(h32 + i + 4);
    float hv[8] = {h0.x, h0.y, h0.z, h0.w, h1.x, h1.y, h1.z, h1.w};
    float ov[8]; V16 ob;
#pragma unroll
    for (int e = 0; e < 8; ++e) {
        float nx = bfl(nb.b[e]) + bfl(r.b[e]) * bfl(hn.b[e]);
        float n = 1.f - 2.f / (__expf(2.f * nx) + 1.f);
        float zv = bfl(z.b[e]);
        ov[e] = (1.f - zv) * n + zv * hv[e];
        ob.b[e] = (__bf16)ov[e];
    }
    *(float4*)(h32 + i)     = make_float4(ov[0], ov[1], ov[2], ov[3]);
    *(float4*)(h32 + i + 4) = make_float4(ov[4], ov[5], ov[6], ov[7]);
    *(int4*)(hbO + (size_t)m * 1024 + c) = ob.i;
}

// ---------------- monotone-uint float max encoding ----------------
__device__ __forceinline__ unsigned fenc(float f) {
    unsigned b = __float_as_uint(f);
    return b ^ (((int)b >> 31) | 0x80000000u);
}
__device__ __forceinline__ float fdec(unsigned u) {
    unsigned b = (u & 0x80000000u) ? (u ^ 0x80000000u) : ~u;
    return __uint_as_float(b);
}

// ---------------- GEMM: out = A(NNxK,lda) @ W^T, 128x128 tile, 2D grid -------
// Depth-2 A pipeline (3 LDS bufs), depth-1 B reg pipeline.
template<int MODE>
__global__ __launch_bounds__(256) void gemm(
    const __hip_bfloat16* __restrict__ A, int lda, int K,
    const int4* __restrict__ Wpk,
    const float* __restrict__ b0, const float* __restrict__ b1,
    __hip_bfloat16* __restrict__ obf, int ldo,
    unsigned* __restrict__ om) {
    __shared__ int4 sA4[3][512];              // 24 KB: A staging; epilogue scratch
    __shared__ unsigned sm[128];
    __hip_bfloat16* lds = (__hip_bfloat16*)sA4;   // epilogue view (64 x 128)
    int bcol = blockIdx.x, brow = blockIdx.y;
    int m0 = brow * 128, n0 = bcol * 128;

    int tid = threadIdx.x;
    int lane = tid & 63, wave = tid >> 6;
    int wr = wave >> 1, wc = wave & 1;
    int lm = lane & 15, quad = lane >> 4;

    const int KT = K >> 5;
    int kbeg = 0, kend = KT;
    if (MODE == 1) {             // skip structurally-zero K halves
        if (bcol >= 12) kbeg = 16;       // hn: inc-half of W is zero
        else if (bcol >= 8) kend = 16;   // i_n: h-half of W is zero
    }
    const int4* Wp = Wpk + ((size_t)bcol * KT << 9) + wc * 256 + lane;

    auto issueA = [&](int kt, int p) {
        int k0 = kt << 5;
#pragma unroll
        for (int it = 0; it < 2; ++it) {
            int idx = it * 256 + tid;
            int row = idx >> 2, kc = idx & 3;
            int gm = m0 + row; gm = gm < NN ? gm : NN - 1;
            gll16(A + (size_t)gm * lda + k0 + kc * 8, (__hip_bfloat16*)(sA4[p]) + idx * 8);
        }
    };

    f32x4 acc[4][4] = {};
    int4 bbC[4], bbN[4];
    issueA(kbeg, 0);
    if (kbeg + 1 < kend) issueA(kbeg + 1, 1);
#pragma unroll
    for (int j = 0; j < 4; ++j) bbC[j] = Wp[((size_t)kbeg << 9) + j * 64];

    for (int kt = kbeg; kt < kend; ++kt) {
        int p = (kt - kbeg) % 3;
        if (kt + 2 < kend) issueA(kt + 2, (kt - kbeg + 2) % 3);
        if (kt + 1 < kend) {
            const int4* wn = Wp + ((size_t)(kt + 1) << 9);
#pragma unroll
            for (int j = 0; j < 4; ++j) bbN[j] = wn[j * 64];
        }
        __builtin_amdgcn_sched_barrier(0);
        if (kt + 2 < kend)      __builtin_amdgcn_s_waitcnt(0xF78);  // vmcnt(8)
        else if (kt + 1 < kend) __builtin_amdgcn_s_waitcnt(0xF76);  // vmcnt(6)
        else                    __builtin_amdgcn_s_waitcnt(0xF70);  // vmcnt(0)
        __builtin_amdgcn_s_barrier();              // tile kt staged for all waves
        __builtin_amdgcn_sched_barrier(0);
        V16 a[4];
#pragma unroll
        for (int i = 0; i < 4; ++i)
            a[i].i = sA4[p][(wr * 64 + i * 16 + lm) * 4 + quad];
#pragma unroll
        for (int i = 0; i < 4; ++i) {
#pragma unroll
            for (int j = 0; j < 4; ++j) {
                V16 b; b.i = bbC[j];
                acc[i][j] = __builtin_amdgcn_mfma_f32_16x16x32_bf16(a[i].b, b.b, acc[i][j], 0, 0, 0);
            }
        }
        __builtin_amdgcn_sched_barrier(0);
        __builtin_amdgcn_s_barrier();              // buf p reusable at iter kt+3
#pragma unroll
        for (int j = 0; j < 4; ++j) bbC[j] = bbN[j];
    }

    if (MODE == 0 || MODE == 1) {
        // LDS-transpose epilogue, 2 row-phases of 64x128 bf16 (coalesced stores)
#pragma unroll
        for (int ph = 0; ph < 2; ++ph) {
            if (wr == ph) {
#pragma unroll
                for (int j = 0; j < 4; ++j) {
                    int c = wc * 64 + j * 16 + lm;
                    int col = n0 + c;
                    float bias = 0.f;
                    if (MODE == 1) {
                        if (col < 1024) bias = b0[col] + b1[col];
                        else if (col < 1536) bias = b0[col];
                        else bias = b1[col - 512];
                    }
#pragma unroll
                    for (int i = 0; i < 4; ++i)
#pragma unroll
                        for (int r = 0; r < 4; ++r) {
                            float v = acc[i][j][r] + bias;
                            if (MODE == 1 && col < 1024) v = 1.f / (1.f + __expf(-v));
                            lds[(i * 16 + quad * 4 + r) * 128 + c] = __float2bfloat16(v);
                        }
                }
            }
            __syncthreads();
#pragma unroll
            for (int q = 0; q < 4; ++q) {
                int idx = q * 256 + tid;
                int rl = idx >> 4, c16 = idx & 15;
                int m = m0 + ph * 64 + rl;
                if (m < NN)
                    *(int4*)(obf + (size_t)m * ldo + n0 + c16 * 8) =
                        *(const int4*)(lds + rl * 128 + c16 * 8);
            }
            __syncthreads();
        }
    } else {   // MODE 3: FC + column max
        if (tid < 128) sm[tid] = 0;
        __syncthreads();
#pragma unroll
        for (int j = 0; j < 4; ++j) {
            int c = wc * 64 + j * 16 + lm;
            float bias = b0[n0 + c];
            float mx = -INFINITY;
#pragma unroll
            for (int i = 0; i < 4; ++i) {
                int r0 = m0 + wr * 64 + i * 16 + quad * 4;
#pragma unroll
                for (int r = 0; r < 4; ++r) {
                    int m = r0 + r;
                    if (m < NN) mx = fmaxf(mx, acc[i][j][r] + bias);
                }
            }
            atomicMax(&sm[c], fenc(mx));
        }
        __syncthreads();
        if (tid < 128) atomicMax(&om[n0 + tid], sm[tid]);
    }
}

__global__ void writeout(const unsigned* __restrict__ om, float* __restrict__ o) {
    int c = threadIdx.x;
    o[c] = fdec(om[c]);
}

// ---------------- launch ----------------
extern "C" void kernel_launch(void* const* d_in, const int* in_sizes, int n_in,
                              void* d_out, int out_size, void* d_ws, size_t ws_size,
                              hipStream_t stream) {
    (void)in_sizes; (void)n_in; (void)out_size; (void)ws_size;
    const float* x    = (const float*)d_in[0];
    const int*   edges= (const int*)d_in[1];
    const float* Wmsg = (const float*)d_in[2];
    const float* bmsg = (const float*)d_in[3];
    const float* Wih  = (const float*)d_in[4];
    const float* Whh  = (const float*)d_in[5];
    const float* bih  = (const float*)d_in[6];
    const float* bhh  = (const float*)d_in[7];
    const float* fcW  = (const float*)d_in[8];
    const float* fcb  = (const float*)d_in[9];
    float* out = (float*)d_out;

    char* ws = (char*)d_ws;
    size_t off = 0;
    auto alloc = [&](size_t bytes) -> void* {
        void* p = ws + off; off += (bytes + 255) & ~(size_t)255; return p;
    };
    float*          h32  = (float*)alloc((size_t)NN * HD * 4);              // 20.5 MB
    __hip_bfloat16* abA  = (__hip_bfloat16*)alloc((size_t)NN * 1024 * 2);   // 20.5 MB
    __hip_bfloat16* abB  = (__hip_bfloat16*)alloc((size_t)NN * 1024 * 2);   // 20.5 MB
    int*            bcnt = (int*)alloc((size_t)NN * NT * 4);                // 160 KB
    int*            bins = (int*)alloc((size_t)NN * NT * CAP * 4);          // 3.8 MB
    unsigned*       om   = (unsigned*)alloc(HD * 4);
    int4*           WmPK   = (int4*)alloc((size_t)2 * 131072 * 16);         // 4.2 MB
    int4*           WrznhPK= (int4*)alloc((size_t)2 * 262144 * 16);         // 8.4 MB
    int4*           WfPK   = (int4*)alloc((size_t)32768 * 16);              // 0.5 MB
    // union: Msg (41 MB) xor RZNH (41 MB)
    char* uni = (char*)alloc((size_t)NN * 2048 * 2);                        // 41 MB
    __hip_bfloat16* Msg  = (__hip_bfloat16*)uni;
    __hip_bfloat16* RZNH = (__hip_bfloat16*)uni;
    // total ~119.5 MB

    hipMemsetAsync(bcnt, 0, (size_t)NN * NT * 4, stream);
    hipMemsetAsync(om, 0, HD * 4, stream);
    prep_all<<<1024 + 2048 + 128 + 5000 + 625, 256, 0, stream>>>(
        Wmsg, Wih, Whh, fcW, x, edges, WmPK, WrznhPK, WfPK, h32, abA, bcnt, bins);

    for (int s = 0; s < 4; ++s) {
        int layer = s >> 1;
        __hip_bfloat16* cur = (s & 1) ? abB : abA;
        __hip_bfloat16* nxt = (s & 1) ? abA : abB;
        const int4* Wm = WmPK + (size_t)layer * 131072;
        const int4* Wz = WrznhPK + (size_t)layer * 262144;
        const float* bm = bmsg + (size_t)layer * 2048;
        const float* bi = bih + (size_t)layer * 1536;
        const float* bh = bhh + (size_t)layer * 1536;

        // Msg = h @ Wm^T  (out 2048, K=512)
        gemm<0><<<dim3(16, GYROWS), 256, 0, stream>>>(cur + 512, 1024, 512, Wm,
            nullptr, nullptr, Msg, 2048, nullptr);
        // inc = gather(Msg) + cnt*bm -> cur[0:512]
        gather_msum<<<NN / 4, 256, 0, stream>>>(bins, bcnt, bm, Msg, cur);
        // RZNH = [sig r | sig z | i_n | hn]  (out 2048, K=1024)
        gemm<1><<<dim3(16, GYROWS), 256, 0, stream>>>(cur, 1024, 1024, Wz,
            bi, bh, RZNH, 2048, nullptr);
        // elementwise GRU combine -> h32, nxt h-slot
        gru_ew<<<NN / 4, 256, 0, stream>>>(RZNH, h32, nxt + 512);
    }
    // FC + column max (final h in abA h-slot after 4 steps)
    gemm<3><<<dim3(4, GYROWS), 256, 0, stream>>>(abA + 512, 1024, 512, WfPK,
        fcb, nullptr, nullptr, 0, om);
    writeout<<<1, 512, 0, stream>>>(om, out);
}

// Round 11
// 718.238 us; speedup vs baseline: 1.1668x; 1.0571x over previous
//
#include <hip/hip_runtime.h>
#include <hip/hip_bf16.h>

// GGNN encoder: N=10000, H=512, T=4, E=40000, L=2 x 2 timesteps.
// fp32 inputs, fp32 output, bf16 MFMA internally.
//
// Per step (2 GEMM dispatches -- algebraic minimum FLOPs):
//   Msg  = h @ Wmsg_cat^T              (N x 2048, K=512)   [MODE 0]
//   inc  = gather-sum(Msg) + cnt*b     (N x 512)           [gather_msum]
//   RZNH = [sig r|sig z|i_n|hn] = [inc|h] @ Wrznh^T + b  (N x 2048, K=1024,
//          per-bcol K-range skips the structurally-zero halves) [MODE 1]
//   h'   = elementwise GRU combine (tanh/blend)            [gru_ew]
// Final: FC + column-max fused [MODE 3] -> writeout.
//
// GEMM r11: BK=64 (was 32). Cross-round evidence: every K-loop variant sits
// at 370-460 TF because fixed cost/iteration (~1275 cyc) dwarfs MFMA
// (~128 cyc); halving iters doubles MFMA per fixed cost. A staged via
// global_load_lds into 3 rotating 16KB LDS bufs (depth-2); B register
// prefetch from packed fragment-order weights; vmcnt(12/8/0) ladder.
// LDS inner layout = two 32-k sub-slabs (bank pattern identical to r10).

#define NN 10000
#define HD 512
#define NT 4
#define NE 40000
#define CAP 24          // max edges per (target,type); P(Poisson(4)>24)~1e-14/bin
#define GYROWS 79       // ceil(10000/128)

typedef __bf16 bf16x8 __attribute__((ext_vector_type(8)));
typedef float f32x4 __attribute__((ext_vector_type(4)));
union V16 { int4 i; bf16x8 b; };

typedef __attribute__((address_space(1))) const unsigned int gu32;
typedef __attribute__((address_space(3))) unsigned int lu32;
__device__ __forceinline__ void gll16(const void* g, void* l) {
    __builtin_amdgcn_global_load_lds((gu32*)g, (lu32*)l, 16, 0, 0);
}

__device__ __forceinline__ float bfl(__bf16 v) { return (float)v; }

// pack 8 fp32 -> int4 of 8 bf16
__device__ __forceinline__ int4 cvt8(const float* __restrict__ s) {
    float4 v0 = *(const float4*)s, v1 = *(const float4*)(s + 4);
    V16 o;
    o.b[0] = (__bf16)v0.x; o.b[1] = (__bf16)v0.y; o.b[2] = (__bf16)v0.z; o.b[3] = (__bf16)v0.w;
    o.b[4] = (__bf16)v1.x; o.b[5] = (__bf16)v1.y; o.b[6] = (__bf16)v1.z; o.b[7] = (__bf16)v1.w;
    return o.i;
}

// Packed-W layout: [ct][kt32][s], s=0..511: wc=s>>8, j=(s>>6)&3, lane=s&63.
// Entry = int4 of W[col][kt32*32+quad*8 .. +8], col = ct*128+wc*64+j*16+(lane&15).
__device__ __forceinline__ void pk_decode(int rem, int KTbits, int& col, int& kk) {
    int ct = rem >> (KTbits + 9);
    int r2 = rem & ((1 << (KTbits + 9)) - 1);
    int kt = r2 >> 9, s = r2 & 511;
    int lane = s & 63;
    col = ct * 128 + ((s >> 8) << 6) + (((s >> 6) & 3) << 4) + (lane & 15);
    kk = kt * 32 + ((lane >> 4) & 3) * 8;
}

// ---------------- fused prep: pack weights, init, bins ----------------------
__global__ void prep_all(const float* __restrict__ Wmsg, const float* __restrict__ Wih,
                         const float* __restrict__ Whh, const float* __restrict__ fcW,
                         const float* __restrict__ x, const int* __restrict__ edges,
                         int4* __restrict__ WmPK, int4* __restrict__ WrznhPK,
                         int4* __restrict__ WfPK,
                         float* __restrict__ h32, __hip_bfloat16* __restrict__ ab,
                         int* __restrict__ bcnt, int* __restrict__ bins) {
    int blk = blockIdx.x, tid = threadIdx.x;
    if (blk < 1024) {            // WmPK: per layer 16ct x 16kt x 512 = 131072
        int g = blk * 256 + tid;
        int l = g >> 17, rem = g & 131071;
        int col, kk; pk_decode(rem, 4, col, kk);
        WmPK[g] = cvt8(Wmsg + (size_t)l * 1048576 + (size_t)col * 512 + kk);
        return;
    }
    blk -= 1024;
    if (blk < 2048) {            // WrznhPK: per layer 16ct x 32kt x 512 = 262144
        int g = blk * 256 + tid;
        int l = g >> 18, rem = g & 262143;
        int col, kk; pk_decode(rem, 5, col, kk);
        int gate = col >> 9, cc = col & 511;   // 0:r 1:z 2:i_n 3:hn
        int4 v = make_int4(0, 0, 0, 0);
        if (kk < 512) {
            if (gate <= 2) v = cvt8(Wih + (size_t)l * 786432 + (size_t)(gate * 512 + cc) * 512 + kk);
        } else {
            if (gate <= 1) v = cvt8(Whh + (size_t)l * 786432 + (size_t)(gate * 512 + cc) * 512 + (kk - 512));
            else if (gate == 3) v = cvt8(Whh + (size_t)l * 786432 + (size_t)(1024 + cc) * 512 + (kk - 512));
        }
        WrznhPK[g] = v;
        return;
    }
    blk -= 2048;
    if (blk < 128) {             // WfPK: 4ct x 16kt x 512 = 32768
        int g = blk * 256 + tid;
        int col, kk; pk_decode(g, 4, col, kk);
        WfPK[g] = cvt8(fcW + (size_t)col * 512 + kk);
        return;
    }
    blk -= 128;
    if (blk < 5000) {            // init: h32 <- x, abA h-slot <- bf16(x)
        int i = blk * 1024 + tid * 4;
        float4 v = *(const float4*)(x + i);
        *(float4*)(h32 + i) = v;
        int m = i >> 9, c = i & 511;
        __hip_bfloat16 o[4] = {__float2bfloat16(v.x), __float2bfloat16(v.y),
                               __float2bfloat16(v.z), __float2bfloat16(v.w)};
        *(ulong1*)(ab + (size_t)m * 1024 + 512 + c) = *(ulong1*)o;
        return;
    }
    blk -= 5000;
    {                            // build_bins
        int i = blk * 256 + tid;
        if (i >= NT * NE) return;
        int src = edges[2 * i], tgt = edges[2 * i + 1];
        int t = i / NE;
        int b = tgt * NT + t;
        int pos = atomicAdd(&bcnt[b], 1);
        if (pos < CAP) bins[(size_t)b * CAP + pos] = src;
    }
}

// ---------------- gather: inc[n][c] = sum_t sum_src Msg[src][t*512+c] + cnt*bm
__global__ __launch_bounds__(256) void gather_msum(
    const int* __restrict__ bins, const int* __restrict__ bcnt,
    const float* __restrict__ bm, const __hip_bfloat16* __restrict__ Msg,
    __hip_bfloat16* __restrict__ inc) {
    int wave = threadIdx.x >> 6, lane = threadIdx.x & 63;
    int n = blockIdx.x * 4 + wave;
    int co = lane * 8;
    float acc[8] = {0, 0, 0, 0, 0, 0, 0, 0};
#pragma unroll
    for (int t = 0; t < NT; ++t) {
        int bi = n * NT + t;
        int cnt = bcnt[bi]; if (cnt > CAP) cnt = CAP;
        const int* bl = bins + (size_t)bi * CAP;
        for (int e = 0; e < cnt; ++e) {
            int src = bl[e];
            V16 v; v.i = *(const int4*)(Msg + (size_t)src * 2048 + t * 512 + co);
#pragma unroll
            for (int k = 0; k < 8; ++k) acc[k] += (float)v.b[k];
        }
        float4 b0 = *(const float4*)(bm + t * 512 + co);
        float4 b1 = *(const float4*)(bm + t * 512 + co + 4);
        float fc = (float)cnt;
        acc[0] += fc * b0.x; acc[1] += fc * b0.y; acc[2] += fc * b0.z; acc[3] += fc * b0.w;
        acc[4] += fc * b1.x; acc[5] += fc * b1.y; acc[6] += fc * b1.z; acc[7] += fc * b1.w;
    }
    V16 o;
#pragma unroll
    for (int k = 0; k < 8; ++k) o.b[k] = (__bf16)acc[k];
    *(int4*)(inc + (size_t)n * 1024 + co) = o.i;
}

// ---------------- elementwise GRU combine ----------------
__global__ __launch_bounds__(256) void gru_ew(
    const __hip_bfloat16* __restrict__ G, float* __restrict__ h32,
    __hip_bfloat16* __restrict__ hbO) {
    int i = (blockIdx.x * 256 + threadIdx.x) * 8;   // over N*512, grid 2500
    int m = i >> 9, c = i & 511;
    const __hip_bfloat16* g = G + (size_t)m * 2048 + c;
    V16 r, z, nb, hn;
    r.i  = *(const int4*)g;
    z.i  = *(const int4*)(g + 512);
    nb.i = *(const int4*)(g + 1024);
    hn.i = *(const int4*)(g + 1536);
    float4 h0 = *(const float4*)(h32 + i), h1 = *(const float4*)(h32 + i + 4);
    float hv[8] = {h0.x, h0.y, h0.z, h0.w, h1.x, h1.y, h1.z, h1.w};
    float ov[8]; V16 ob;
#pragma unroll
    for (int e = 0; e < 8; ++e) {
        float nx = bfl(nb.b[e]) + bfl(r.b[e]) * bfl(hn.b[e]);
        float n = 1.f - 2.f / (__expf(2.f * nx) + 1.f);
        float zv = bfl(z.b[e]);
        ov[e] = (1.f - zv) * n + zv * hv[e];
        ob.b[e] = (__bf16)ov[e];
    }
    *(float4*)(h32 + i)     = make_float4(ov[0], ov[1], ov[2], ov[3]);
    *(float4*)(h32 + i + 4) = make_float4(ov[4], ov[5], ov[6], ov[7]);
    *(int4*)(hbO + (size_t)m * 1024 + c) = ob.i;
}

// ---------------- monotone-uint float max encoding ----------------
__device__ __forceinline__ unsigned fenc(float f) {
    unsigned b = __float_as_uint(f);
    return b ^ (((int)b >> 31) | 0x80000000u);
}
__device__ __forceinline__ float fdec(unsigned u) {
    unsigned b = (u & 0x80000000u) ? (u ^ 0x80000000u) : ~u;
    return __uint_as_float(b);
}

// ---------------- GEMM: out = A(NNxK,lda) @ W^T, 128x128 tile, BK=64 ---------
// Depth-2 A pipeline (3 x 16KB LDS bufs), B reg prefetch. vmcnt(12/8/0).
template<int MODE>
__global__ __launch_bounds__(256) void gemm(
    const __hip_bfloat16* __restrict__ A, int lda, int K,
    const int4* __restrict__ Wpk,
    const float* __restrict__ b0, const float* __restrict__ b1,
    __hip_bfloat16* __restrict__ obf, int ldo,
    unsigned* __restrict__ om) {
    __shared__ int4 sA4[3][1024];             // 48 KB: A staging; epilogue scratch
    __shared__ unsigned sm[128];
    __hip_bfloat16* lds = (__hip_bfloat16*)sA4;   // epilogue view (64 x 128)
    int bcol = blockIdx.x, brow = blockIdx.y;
    int m0 = brow * 128, n0 = bcol * 128;

    int tid = threadIdx.x;
    int lane = tid & 63, wave = tid >> 6;
    int wr = wave >> 1, wc = wave & 1;
    int lm = lane & 15, quad = lane >> 4;

    const int KT32 = K >> 5;
    const int KT = K >> 6;       // BK64 tiles
    int kbeg = 0, kend = KT;
    if (MODE == 1) {             // skip structurally-zero K halves
        if (bcol >= 12) kbeg = 8;        // hn: inc-half of W is zero
        else if (bcol >= 8) kend = 8;    // i_n: h-half of W is zero
    }
    const int4* Wp = Wpk + ((size_t)bcol * KT32 << 9) + wc * 256 + lane;

    // LDS per tile = two 32-k sub-slabs of 512 int4 (identical pattern to BK32)
    auto issueA = [&](int kt, int p) {
        int k0 = kt << 6;
#pragma unroll
        for (int it = 0; it < 4; ++it) {
            int idx = it * 256 + tid;
            int s = idx >> 9, rem = idx & 511;
            int row = rem >> 2, kc = rem & 3;
            int gm = m0 + row; gm = gm < NN ? gm : NN - 1;
            gll16(A + (size_t)gm * lda + k0 + s * 32 + kc * 8,
                  (__hip_bfloat16*)(sA4[p]) + idx * 8);
        }
    };
    auto loadB = [&](int kt, int4 bb[2][4]) {
#pragma unroll
        for (int s = 0; s < 2; ++s) {
            const int4* wn = Wp + ((size_t)(2 * kt + s) << 9);
#pragma unroll
            for (int j = 0; j < 4; ++j) bb[s][j] = wn[j * 64];
        }
    };

    f32x4 acc[4][4] = {};
    int4 bbC[2][4], bbN[2][4];
    issueA(kbeg, 0);
    if (kbeg + 1 < kend) issueA(kbeg + 1, 1);
    loadB(kbeg, bbC);

    for (int kt = kbeg; kt < kend; ++kt) {
        int p = (kt - kbeg) % 3;
        if (kt + 2 < kend) issueA(kt + 2, (kt - kbeg + 2) % 3);
        if (kt + 1 < kend) loadB(kt + 1, bbN);
        __builtin_amdgcn_sched_barrier(0);
        if (kt + 2 < kend)      __builtin_amdgcn_s_waitcnt(0xF7C);  // vmcnt(12)
        else if (kt + 1 < kend) __builtin_amdgcn_s_waitcnt(0xF78);  // vmcnt(8)
        else                    __builtin_amdgcn_s_waitcnt(0xF70);  // vmcnt(0)
        __builtin_amdgcn_s_barrier();              // tile kt staged for all waves
        __builtin_amdgcn_sched_barrier(0);
        V16 a[4][2];
#pragma unroll
        for (int i = 0; i < 4; ++i)
#pragma unroll
            for (int s = 0; s < 2; ++s)
                a[i][s].i = sA4[p][s * 512 + (wr * 64 + i * 16 + lm) * 4 + quad];
#pragma unroll
        for (int s = 0; s < 2; ++s)
#pragma unroll
            for (int i = 0; i < 4; ++i)
#pragma unroll
                for (int j = 0; j < 4; ++j) {
                    V16 b; b.i = bbC[s][j];
                    acc[i][j] = __builtin_amdgcn_mfma_f32_16x16x32_bf16(a[i][s].b, b.b, acc[i][j], 0, 0, 0);
                }
        __builtin_amdgcn_sched_barrier(0);
        __builtin_amdgcn_s_barrier();              // buf p reusable at iter kt+3
#pragma unroll
        for (int s = 0; s < 2; ++s)
#pragma unroll
            for (int j = 0; j < 4; ++j) bbC[s][j] = bbN[s][j];
    }

    if (MODE == 0 || MODE == 1) {
        // LDS-transpose epilogue, 2 row-phases of 64x128 bf16 (coalesced stores)
#pragma unroll
        for (int ph = 0; ph < 2; ++ph) {
            if (wr == ph) {
#pragma unroll
                for (int j = 0; j < 4; ++j) {
                    int c = wc * 64 + j * 16 + lm;
                    int col = n0 + c;
                    float bias = 0.f;
                    if (MODE == 1) {
                        if (col < 1024) bias = b0[col] + b1[col];
                        else if (col < 1536) bias = b0[col];
                        else bias = b1[col - 512];
                    }
#pragma unroll
                    for (int i = 0; i < 4; ++i)
#pragma unroll
                        for (int r = 0; r < 4; ++r) {
                            float v = acc[i][j][r] + bias;
                            if (MODE == 1 && col < 1024) v = 1.f / (1.f + __expf(-v));
                            lds[(i * 16 + quad * 4 + r) * 128 + c] = __float2bfloat16(v);
                        }
                }
            }
            __syncthreads();
#pragma unroll
            for (int q = 0; q < 4; ++q) {
                int idx = q * 256 + tid;
                int rl = idx >> 4, c16 = idx & 15;
                int m = m0 + ph * 64 + rl;
                if (m < NN)
                    *(int4*)(obf + (size_t)m * ldo + n0 + c16 * 8) =
                        *(const int4*)(lds + rl * 128 + c16 * 8);
            }
            __syncthreads();
        }
    } else {   // MODE 3: FC + column max
        if (tid < 128) sm[tid] = 0;
        __syncthreads();
#pragma unroll
        for (int j = 0; j < 4; ++j) {
            int c = wc * 64 + j * 16 + lm;
            float bias = b0[n0 + c];
            float mx = -INFINITY;
#pragma unroll
            for (int i = 0; i < 4; ++i) {
                int r0 = m0 + wr * 64 + i * 16 + quad * 4;
#pragma unroll
                for (int r = 0; r < 4; ++r) {
                    int m = r0 + r;
                    if (m < NN) mx = fmaxf(mx, acc[i][j][r] + bias);
                }
            }
            atomicMax(&sm[c], fenc(mx));
        }
        __syncthreads();
        if (tid < 128) atomicMax(&om[n0 + tid], sm[tid]);
    }
}

__global__ void writeout(const unsigned* __restrict__ om, float* __restrict__ o) {
    int c = threadIdx.x;
    o[c] = fdec(om[c]);
}

// ---------------- launch ----------------
extern "C" void kernel_launch(void* const* d_in, const int* in_sizes, int n_in,
                              void* d_out, int out_size, void* d_ws, size_t ws_size,
                              hipStream_t stream) {
    (void)in_sizes; (void)n_in; (void)out_size; (void)ws_size;
    const float* x    = (const float*)d_in[0];
    const int*   edges= (const int*)d_in[1];
    const float* Wmsg = (const float*)d_in[2];
    const float* bmsg = (const float*)d_in[3];
    const float* Wih  = (const float*)d_in[4];
    const float* Whh  = (const float*)d_in[5];
    const float* bih  = (const float*)d_in[6];
    const float* bhh  = (const float*)d_in[7];
    const float* fcW  = (const float*)d_in[8];
    const float* fcb  = (const float*)d_in[9];
    float* out = (float*)d_out;

    char* ws = (char*)d_ws;
    size_t off = 0;
    auto alloc = [&](size_t bytes) -> void* {
        void* p = ws + off; off += (bytes + 255) & ~(size_t)255; return p;
    };
    float*          h32  = (float*)alloc((size_t)NN * HD * 4);              // 20.5 MB
    __hip_bfloat16* abA  = (__hip_bfloat16*)alloc((size_t)NN * 1024 * 2);   // 20.5 MB
    __hip_bfloat16* abB  = (__hip_bfloat16*)alloc((size_t)NN * 1024 * 2);   // 20.5 MB
    int*            bcnt = (int*)alloc((size_t)NN * NT * 4);                // 160 KB
    int*            bins = (int*)alloc((size_t)NN * NT * CAP * 4);          // 3.8 MB
    unsigned*       om   = (unsigned*)alloc(HD * 4);
    int4*           WmPK   = (int4*)alloc((size_t)2 * 131072 * 16);         // 4.2 MB
    int4*           WrznhPK= (int4*)alloc((size_t)2 * 262144 * 16);         // 8.4 MB
    int4*           WfPK   = (int4*)alloc((size_t)32768 * 16);              // 0.5 MB
    // union: Msg (41 MB) xor RZNH (41 MB)
    char* uni = (char*)alloc((size_t)NN * 2048 * 2);                        // 41 MB
    __hip_bfloat16* Msg  = (__hip_bfloat16*)uni;
    __hip_bfloat16* RZNH = (__hip_bfloat16*)uni;
    // total ~119.5 MB

    hipMemsetAsync(bcnt, 0, (size_t)NN * NT * 4, stream);
    hipMemsetAsync(om, 0, HD * 4, stream);
    prep_all<<<1024 + 2048 + 128 + 5000 + 625, 256, 0, stream>>>(
        Wmsg, Wih, Whh, fcW, x, edges, WmPK, WrznhPK, WfPK, h32, abA, bcnt, bins);

    for (int s = 0; s < 4; ++s) {
        int layer = s >> 1;
        __hip_bfloat16* cur = (s & 1) ? abB : abA;
        __hip_bfloat16* nxt = (s & 1) ? abA : abB;
        const int4* Wm = WmPK + (size_t)layer * 131072;
        const int4* Wz = WrznhPK + (size_t)layer * 262144;
        const float* bm = bmsg + (size_t)layer * 2048;
        const float* bi = bih + (size_t)layer * 1536;
        const float* bh = bhh + (size_t)layer * 1536;

        // Msg = h @ Wm^T  (out 2048, K=512)
        gemm<0><<<dim3(16, GYROWS), 256, 0, stream>>>(cur + 512, 1024, 512, Wm,
            nullptr, nullptr, Msg, 2048, nullptr);
        // inc = gather(Msg) + cnt*bm -> cur[0:512]
        gather_msum<<<NN / 4, 256, 0, stream>>>(bins, bcnt, bm, Msg, cur);
        // RZNH = [sig r | sig z | i_n | hn]  (out 2048, K=1024)
        gemm<1><<<dim3(16, GYROWS), 256, 0, stream>>>(cur, 1024, 1024, Wz,
            bi, bh, RZNH, 2048, nullptr);
        // elementwise GRU combine -> h32, nxt h-slot
        gru_ew<<<NN / 4, 256, 0, stream>>>(RZNH, h32, nxt + 512);
    }
    // FC + column max (final h in abA h-slot after 4 steps)
    gemm<3><<<dim3(4, GYROWS), 256, 0, stream>>>(abA + 512, 1024, 512, WfPK,
        fcb, nullptr, nullptr, 0, om);
    writeout<<<1, 512, 0, stream>>>(om, out);
}